// Round 10
// baseline (674.133 us; speedup 1.0000x reference)
//
#include <hip/hip_runtime.h>

// ---------------------------------------------------------------------------
// StyleGAN2 SynthesisBlock, MFMA f16, round 10 (= round 9 + xprep grid fix).
//   modconv(x, kernel, s) == demod[b,o] * conv2d(x * s[b,i], kernel)
// Pipeline: xprep (x*s1 -> f16 x1m); conv1 reads x1m, writes h2m=lrelu(..)*s2;
// conv2 reads h2m, writes pixel-shuffled f32 out.
// Conv kernel: one y-row per block. A (66-px halo x K=256) staged in LDS per
// dy (pure f16 copy, 2 barriers per dy = 6/block). B read DIRECTLY from
// global (L2-resident Bt[9][COUT][256]) into registers - no B LDS at all.
// Wave tile 64px x 128ch (4m x 8n frags of v_mfma_f32_16x16x32_f16):
// A-LDS bytes/MFMA = 128 B (was 256+256).
// ---------------------------------------------------------------------------

typedef _Float16 half4 __attribute__((ext_vector_type(4)));
typedef _Float16 half8 __attribute__((ext_vector_type(8)));
typedef float f32x4 __attribute__((ext_vector_type(4)));

__global__ __launch_bounds__(256) void style_kernel(
    const float* __restrict__ w, const float* __restrict__ a1w, const float* __restrict__ a1b,
    const float* __restrict__ a2w, const float* __restrict__ a2b,
    float* __restrict__ s1, float* __restrict__ s2)
{
  const int b = blockIdx.x, c = threadIdx.x;
  const float* wb = w + b * 128;
  float acc1 = 0.f, acc2 = 0.f;
  for (int k = 0; k < 128; ++k) {
    const float wv = wb[k];
    acc1 = fmaf(wv, a1w[k * 256 + c], acc1);
    acc2 = fmaf(wv, a2w[k * 256 + c], acc2);
  }
  s1[b * 256 + c] = acc1 + a1b[c];
  s2[b * 256 + c] = acc2 + a2b[c];
}

__global__ __launch_bounds__(256) void ksq_kernel(
    const float* __restrict__ kern, float* __restrict__ ksq, int n)
{
  const int i = blockIdx.x * 256 + threadIdx.x;
  if (i < n) {
    float acc = 0.f;
    for (int t = 0; t < 9; ++t) { const float v = kern[t * n + i]; acc = fmaf(v, v, acc); }
    ksq[i] = acc;
  }
}

__global__ __launch_bounds__(256) void demod_kernel(
    const float* __restrict__ s, const float* __restrict__ ksq,
    float* __restrict__ demod, int cout)
{
  const int b = blockIdx.y;
  const int o = blockIdx.x * 256 + threadIdx.x;
  const float* sb = s + b * 256;
  float acc = 1e-8f;
  for (int i = 0; i < 256; ++i) {
    const float sv = sb[i];
    acc = fmaf(sv * sv, ksq[i * cout + o], acc);
  }
  demod[b * cout + o] = 1.0f / sqrtf(acc);
}

// Kw[9][256][COUT] f32 -> Bt[9][COUT][256] f16  (per-tap transpose + convert)
__global__ __launch_bounds__(256) void kprep_kernel(
    const float* __restrict__ Kw, _Float16* __restrict__ Bt, int cout)
{
  __shared__ float T[64][68];
  const int tap = blockIdx.z;
  const int o0 = blockIdx.x * 64, c0 = blockIdx.y * 64;
  const int t = threadIdx.x;
  #pragma unroll
  for (int it = 0; it < 4; ++it) {
    const int c = (t >> 4) + it * 16;
    const int o = (t & 15) * 4;
    *(float4*)(&T[c][o]) = *(const float4*)(Kw + ((size_t)tap * 256 + c0 + c) * cout + o0 + o);
  }
  __syncthreads();
  #pragma unroll
  for (int it = 0; it < 4; ++it) {
    const int o = (t >> 4) + it * 16;
    const int c = (t & 15) * 4;
    half4 hv = {(_Float16)T[c][o], (_Float16)T[c + 1][o],
                (_Float16)T[c + 2][o], (_Float16)T[c + 3][o]};
    *(half4*)(&Bt[((size_t)tap * cout + o0 + o) * 256 + c0 + c]) = hv;
  }
}

// x1m[b,y,x,c] = (f16)(x * s1[b,c])   (half8 per thread)
// 16*64*64*256 elems = 2,097,152 half8  ->  grid 8192 x 256
__global__ __launch_bounds__(256) void xprep_kernel(
    const float* __restrict__ X, const float* __restrict__ S, _Float16* __restrict__ O)
{
  const int i = blockIdx.x * 256 + threadIdx.x;   // half8 index
  const int b = i >> 17;                          // 2^17 half8 per batch
  const int c8 = (i & 31) * 8;
  const float4 x0 = *(const float4*)(X + (size_t)i * 8);
  const float4 x1 = *(const float4*)(X + (size_t)i * 8 + 4);
  const float4 s0 = *(const float4*)(S + b * 256 + c8);
  const float4 s1v = *(const float4*)(S + b * 256 + c8 + 4);
  half8 hv;
  hv[0] = (_Float16)(x0.x * s0.x);  hv[1] = (_Float16)(x0.y * s0.y);
  hv[2] = (_Float16)(x0.z * s0.z);  hv[3] = (_Float16)(x0.w * s0.w);
  hv[4] = (_Float16)(x1.x * s1v.x); hv[5] = (_Float16)(x1.y * s1v.y);
  hv[6] = (_Float16)(x1.z * s1v.z); hv[7] = (_Float16)(x1.w * s1v.w);
  *(half8*)(&O[(size_t)i * 8]) = hv;
}

// Conv: block = one y-row (64 px), all COUT channels. NTHR/64 waves, each
// wave 64px x 128ch (4m x 8n x 16x16x32 frags). A in LDS, B from global.
template <int COUT, bool SHUFFLE, int NTHR>
__global__ __launch_bounds__(NTHR, 2) void conv_mfma(
    const _Float16* __restrict__ X,   // [16,64,64,256] pre-modulated f16
    const _Float16* __restrict__ Bt,  // [9,COUT,256] f16
    const float* __restrict__ D,      // [16,COUT] demod
    const float* __restrict__ NZ,     // [16,64,64,1]
    const float* __restrict__ NSp,    // [1]
    const float* __restrict__ BIAS,   // [COUT]
    const float* __restrict__ SMOD,   // [16,256] s2 (!SHUFFLE: h2m = v*s2)
    void* __restrict__ OUTv)
{
  __shared__ __align__(16) _Float16 As[66][264];   // 66 halo rows x K=256 (+8 pad)

  const int t = threadIdx.x;
  // bijective XCD swizzle over 1024 row-blocks: XCD k gets 128 contiguous rows
  const int lin = blockIdx.x;
  const int wgid = (lin & 7) * 128 + (lin >> 3);
  const int b = wgid >> 6, y = wgid & 63;

  const int lane = t & 63, wn = t >> 6;       // wave covers ch [wn*128, +128)
  const int lrow = lane >> 4, lcol = lane & 15;
  const int o0w = wn * 128;

  f32x4 acc[4][8];
  #pragma unroll
  for (int m = 0; m < 4; ++m)
    #pragma unroll
    for (int n = 0; n < 8; ++n)
      acc[m][n] = (f32x4){0.f, 0.f, 0.f, 0.f};

  const int scol = (t & 31) * 8;              // staging: 32 thr/row, half8 each

  for (int dyi = 0; dyi < 3; ++dyi) {
    const int ys = y + dyi - 1;
    const bool vrow = ((unsigned)ys < 64u);
    const _Float16* Xrow = X + (((size_t)(b * 64 + (vrow ? ys : 0))) * 64) * 256;

    __syncthreads();   // previous dy's reads done before overwrite
    for (int r = (t >> 5); r < 66; r += (NTHR >> 5)) {
      const int xs = r - 1;
      half8 hv = {};
      if (vrow && (unsigned)xs < 64u)
        hv = *(const half8*)(Xrow + (size_t)xs * 256 + scol);
      *(half8*)(&As[r][scol]) = hv;
    }
    __syncthreads();

    for (int dxi = 0; dxi < 3; ++dxi) {
      const _Float16* Bp = Bt + ((size_t)(dyi * 3 + dxi) * COUT + o0w) * 256
                         + (size_t)lcol * 256 + lrow * 8;
      #pragma unroll 1
      for (int c0 = 0; c0 < 256; c0 += 64) {
        half8 bf[8][2];
        #pragma unroll
        for (int n = 0; n < 8; ++n)
          #pragma unroll
          for (int ks = 0; ks < 2; ++ks)
            bf[n][ks] = *(const half8*)(Bp + (size_t)n * 16 * 256 + c0 + ks * 32);
        half8 af[4][2];
        #pragma unroll
        for (int m = 0; m < 4; ++m)
          #pragma unroll
          for (int ks = 0; ks < 2; ++ks)
            af[m][ks] = *(const half8*)(&As[dxi + m * 16 + lcol][c0 + ks * 32 + lrow * 8]);
        #pragma unroll
        for (int ks = 0; ks < 2; ++ks)
          #pragma unroll
          for (int m = 0; m < 4; ++m)
            #pragma unroll
            for (int n = 0; n < 8; ++n)
              acc[m][n] = __builtin_amdgcn_mfma_f32_16x16x32_f16(af[m][ks], bf[n][ks], acc[m][n], 0, 0, 0);
      }
    }
  }

  // ---- epilogue: C/D layout col = lane&15, row = (lane>>4)*4 + rr [m89]
  const float ns = NSp[0];
  float nzv[4][4];
  #pragma unroll
  for (int m = 0; m < 4; ++m)
    #pragma unroll
    for (int rr = 0; rr < 4; ++rr)
      nzv[m][rr] = NZ[(size_t)(b * 64 + y) * 64 + m * 16 + lrow * 4 + rr] * ns;

  #pragma unroll
  for (int n = 0; n < 8; ++n) {
    const int o = o0w + n * 16 + lcol;
    const float dmv = D[b * COUT + o];
    const float bv = BIAS[o];
    float smv = 1.0f;
    if constexpr (!SHUFFLE) smv = SMOD[b * 256 + o];
    #pragma unroll
    for (int m = 0; m < 4; ++m) {
      #pragma unroll
      for (int rr = 0; rr < 4; ++rr) {
        const int p = m * 16 + lrow * 4 + rr;
        float v = fmaf(acc[m][n][rr], dmv, nzv[m][rr] + bv);
        v = fmaxf(v, 0.2f * v);                    // leaky_relu(0.2)
        if constexpr (!SHUFFLE) {
          ((_Float16*)OUTv)[((size_t)(b * 64 + y) * 64 + p) * COUT + o] = (_Float16)(v * smv);
        } else {
          // COUT=512: full ch o = wn*128 + c; g=wn -> out[b,2y+sh,2x+sw,c]
          const int c = n * 16 + lcol;
          const int sh = wn >> 1, sw = wn & 1;
          ((float*)OUTv)[(((size_t)(b * 128) + 2 * y + sh) * 128 + (2 * p + sw)) * 128 + c] = v;
        }
      }
    }
  }
}

extern "C" void kernel_launch(void* const* d_in, const int* in_sizes, int n_in,
                              void* d_out, int out_size, void* d_ws, size_t ws_size,
                              hipStream_t stream)
{
  const float* x   = (const float*)d_in[0];
  const float* w   = (const float*)d_in[1];
  const float* a1w = (const float*)d_in[2];
  const float* a1b = (const float*)d_in[3];
  const float* k1  = (const float*)d_in[4];
  const float* ns1 = (const float*)d_in[5];
  const float* b1  = (const float*)d_in[6];
  const float* a2w = (const float*)d_in[7];
  const float* a2b = (const float*)d_in[8];
  const float* k2  = (const float*)d_in[9];
  const float* ns2 = (const float*)d_in[10];
  const float* b2  = (const float*)d_in[11];
  const float* nz1 = (const float*)d_in[12];
  const float* nz2 = (const float*)d_in[13];
  float* out = (float*)d_out;

  float* ws = (float*)d_ws;
  float* s1   = ws;              // [16,256]
  float* s2   = ws + 4096;       // [16,256]
  float* ksq1 = ws + 8192;       // [256,256]
  float* ksq2 = ws + 73728;      // [256,512]
  float* dm1  = ws + 204800;     // [16,256]
  float* dm2  = ws + 208896;     // [16,512]
  _Float16* Bt1 = (_Float16*)(ws + 217088);     // [9,256,256] f16
  _Float16* Bt2 = Bt1 + 9 * 256 * 256;          // [9,512,256] f16
  _Float16* h2m = Bt2 + 9 * 512 * 256;          // [16,64,64,256] f16 = lrelu*s2
  _Float16* x1m = h2m + 16 * 64 * 64 * 256;     // [16,64,64,256] f16 = x*s1

  style_kernel<<<16, 256, 0, stream>>>(w, a1w, a1b, a2w, a2b, s1, s2);
  ksq_kernel<<<65536 / 256, 256, 0, stream>>>(k1, ksq1, 65536);
  ksq_kernel<<<131072 / 256, 256, 0, stream>>>(k2, ksq2, 131072);
  demod_kernel<<<dim3(1, 16), 256, 0, stream>>>(s1, ksq1, dm1, 256);
  demod_kernel<<<dim3(2, 16), 256, 0, stream>>>(s2, ksq2, dm2, 512);
  kprep_kernel<<<dim3(4, 4, 9), 256, 0, stream>>>(k1, Bt1, 256);
  kprep_kernel<<<dim3(8, 4, 9), 256, 0, stream>>>(k2, Bt2, 512);
  // 2,097,152 half8 / 256 thr = 8192 blocks  (round-9 bug: was 2048 -> 3/4 of
  // x1m left poisoned)
  xprep_kernel<<<8192, 256, 0, stream>>>(x, s1, x1m);

  // conv1: 2 waves (COUT=256), writes h2m f16; conv2: 4 waves (512), shuffle
  conv_mfma<256, false, 128><<<1024, 128, 0, stream>>>(
      x1m, Bt1, dm1, nz1, ns1, b1, s2, (void*)h2m);
  conv_mfma<512, true, 256><<<1024, 256, 0, stream>>>(
      h2m, Bt2, dm2, nz2, ns2, b2, nullptr, (void*)out);
}